// Round 4
// baseline (192.295 us; speedup 1.0000x reference)
//
#include <hip/hip_runtime.h>
#include <hip/hip_bf16.h>
#include <stdint.h>

#define B_    16
#define CIN_  512
#define COUT_ 512
#define K_    3
#define T_    2048
#define S_    128
#define TP_   2064          // padded t rows: row = t+8, 8-row zero halo each side
#define CXP_  2050          // padded column-sum: idx = t+1, zero at both ends
#define XS_SZ 17408         // B tile: 4 g x 272 rows x 16B
#define NBUF  3

#define LIN_SCALE  0.08838834764831845f   // 1/sqrt(128)
#define CONV_SCALE 0.014731391274719739f  // 1/sqrt(512*9)

typedef unsigned short u16;
typedef short s16x8 __attribute__((ext_vector_type(8)));
typedef float f32x4 __attribute__((ext_vector_type(4)));
typedef u16 u16x8 __attribute__((ext_vector_type(8)));

__device__ __forceinline__ u16 bf16r(float f) {
    uint32_t u = __float_as_uint(f);
    return (u16)((u + 0x7FFFu + ((u >> 16) & 1u)) >> 16);   // RNE
}

#define GLDS16(gsrc, ldst) \
    __builtin_amdgcn_global_load_lds((__attribute__((address_space(1))) void*)(gsrc), \
                                     (__attribute__((address_space(3))) void*)(ldst), 16, 0, 0)

// ---------------- K1: style projection  s[b,i]
__global__ void k_style(const float* __restrict__ c_trg,
                        const float* __restrict__ style_w,
                        const float* __restrict__ style_b,
                        float* __restrict__ s_out) {
    int idx = blockIdx.x * 256 + threadIdx.x;       // 0..8191
    int b = idx >> 9, i = idx & 511;
    const float4* c4 = reinterpret_cast<const float4*>(c_trg + b * S_);
    const float4* w4 = reinterpret_cast<const float4*>(style_w + (size_t)i * S_);
    float acc = 0.f;
#pragma unroll
    for (int j = 0; j < S_ / 4; ++j) {
        float4 a = c4[j], w = w4[j];
        acc += a.x * w.x + a.y * w.y + a.z * w.z + a.w * w.w;
    }
    s_out[idx] = acc * LIN_SCALE + style_b[i];
}

// ---------------- K2a: per-(o,i) tap sums:  W1 = sum_k (w+1), W2 = sum_k (w+1)^2
__global__ void k_wsum(const float* __restrict__ conv_w,
                       float* __restrict__ W1, float* __restrict__ W2) {
    int idx = blockIdx.x * 256 + threadIdx.x;   // o*512 + i
    const float* wr = conv_w + (size_t)idx * 3;
    float a0 = wr[0] + 1.f, a1 = wr[1] + 1.f, a2 = wr[2] + 1.f;
    W1[idx] = a0 + a1 + a2;
    W2[idx] = a0 * a0 + a1 * a1 + a2 * a2;
}

// ---------------- K2b: alpha/beta per (b,o) via GEMV on W1/W2. 1 wave per (b,o).
__global__ void k_stats2(const float* __restrict__ s,
                         const float* __restrict__ W1, const float* __restrict__ W2,
                         float* __restrict__ alpha, float* __restrict__ beta) {
    int bo = blockIdx.x;          // b*512 + o
    int b = bo >> 9, o = bo & 511;
    const float* sb = s + b * CIN_;
    const float* w1 = W1 + (size_t)o * CIN_;
    const float* w2 = W2 + (size_t)o * CIN_;
    int l = threadIdx.x;
    float sum = 0.f, sq = 0.f;
#pragma unroll
    for (int r = 0; r < 8; ++r) {
        float sv = sb[l + r * 64];
        sum += sv * w1[l + r * 64];
        sq  += sv * sv * w2[l + r * 64];
    }
#pragma unroll
    for (int off = 32; off; off >>= 1) { sum += __shfl_down(sum, off); sq += __shfl_down(sq, off); }
    if (l == 0) {
        float mean  = CONV_SCALE * sum * (1.0f / (CIN_ * K_));
        float demod = rsqrtf(CONV_SCALE * CONV_SCALE * sq + 1e-8f);
        alpha[bo] = demod * CONV_SCALE;
        beta[bo]  = demod * mean;
    }
}

// ---------------- K3: weight prepack into MFMA fragment-image order (bf16).
// wpk flat idx = ((((ob*16 + step)*3 + tap)*8 + grp)*64 + lane)*8 + j
// holds cw[o = ob*128+grp*16+(lane&15)][i = step*32+(lane>>4)*8+j][tap]
__global__ void k_prep_w(const float* __restrict__ conv_w, u16* __restrict__ wpk) {
    int idx = blockIdx.x * 256 + threadIdx.x;   // < 786432
    int j    = idx & 7;
    int lane = (idx >> 3) & 63;
    int grp  = (idx >> 9) & 7;
    int rest = idx >> 12;          // tap + 3*(step + 16*ob)
    int tap  = rest % 3;
    int so   = rest / 3;
    int step = so & 15, ob = so >> 4;
    int o = ob * 128 + grp * 16 + (lane & 15);
    int i = step * 32 + (lane >> 4) * 8 + j;
    wpk[idx] = bf16r(conv_w[((size_t)o * CIN_ + i) * 3 + tap]);
}

// ---------------- K4: y = s*x -> bf16, octet-interleaved + t-halo; 64 channels/block,
// 8 atomicAdds per (b,t) for column sums.
__global__ void k_ytrans(const float* __restrict__ x, const float* __restrict__ s,
                         u16* __restrict__ ybf,
                         float* __restrict__ cxp, float* __restrict__ cyp) {
    int tid = threadIdx.x;
    int t = blockIdx.x * 256 + tid;
    int og = blockIdx.y, b = blockIdx.z;
    float ax = 0.f, ay = 0.f;
#pragma unroll
    for (int o8 = 0; o8 < 8; ++o8) {
        int oct = og * 8 + o8;
        const float* xb = x + ((size_t)(b * CIN_ + oct * 8)) * T_ + t;
        const float* sb = s + b * CIN_ + oct * 8;
        u16x8 pv;
#pragma unroll
        for (int j = 0; j < 8; ++j) {
            float xv = xb[(size_t)j * T_];
            float yv = sb[j] * xv;
            ax += xv; ay += yv;
            pv[j] = bf16r(yv);
        }
        *(u16x8*)(ybf + (((size_t)(b * 64 + oct)) * TP_ + t + 8) * 8) = pv;
    }
    atomicAdd(&cxp[b * CXP_ + t + 1], ax);
    atomicAdd(&cyp[b * CXP_ + t + 1], ay);
    if (blockIdx.x == 0 && tid < 64) {      // zero both halos for this block's 8 octs
        u16x8 z = {0, 0, 0, 0, 0, 0, 0, 0};
        int oct = og * 8 + (tid >> 3);
        *(u16x8*)(ybf + (((size_t)(b * 64 + oct)) * TP_ + (tid & 7)) * 8) = z;
        *(u16x8*)(ybf + (((size_t)(b * 64 + oct)) * TP_ + 2056 + (tid & 7)) * 8) = z;
    }
}

// ---------------- K5: MFMA conv v3. 128o x 256t tile, 8 waves.
// A: global->reg direct (fragment-image order, reg-dbuf 1 step ahead).
// B: LDS triple-buffer, staged 2 steps ahead via global_load_lds.
// Sync: one raw s_barrier/step; B readiness implied by in-order vmcnt +
// compiler's wait on A-loads (issued after the older B-stage GLDS).
__global__ __launch_bounds__(512) void k_conv(
    const u16* __restrict__ wpk, const u16* __restrict__ ybf,
    const float* __restrict__ alpha, const float* __restrict__ beta,
    const float* __restrict__ cxp, const float* __restrict__ cyp,
    float* __restrict__ out) {

    __shared__ __align__(16) char smem[NBUF * XS_SZ];   // 52224 B

    const int tid  = threadIdx.x;
    const int lane = tid & 63;
    const int w    = tid >> 6;
    const int wr   = w >> 2, wc = w & 3;

    // XCD swizzle: 512 blocks, 64 contiguous wgs per XCD -> 2 batches per XCD L2
    const int bid = blockIdx.x;
    const int wg  = (bid & 7) * 64 + (bid >> 3);
    const int b   = wg >> 5;
    const int ob  = (wg >> 3) & 3;
    const int t0  = (wg & 7) * 256;

    // B staging rows (1088 = 4 g x 272): r0 = tid, r1 = 512+tid, r2 = lanes<8 each wave
    const int row0 = tid, row1 = 512 + tid, row2 = 1024 + w * 8 + (lane & 7);
    const int g0 = row0 / 272, rr0 = row0 - g0 * 272;
    const int g1 = row1 / 272, rr1 = row1 - g1 * 272;
    const int g2 = row2 / 272, rr2 = row2 - g2 * 272;

    const char* ybase = (const char*)ybf + ((size_t)b * 64) * (TP_ * 16);
    const char* abase = (const char*)wpk + (size_t)ob * 393216 + (wr * 4) * 1024 + lane * 16;
    const int xs_lane = (lane >> 4) * 4352 + ((lane & 15) + 7) * 16 + wc * 1024;

    f32x4 acc[4][4] = {};
    s16x8 afA[12], afB[12];

#define STAGEB(s)                                                                        \
    do {                                                                                 \
        char* bb = smem + ((s) % NBUF) * XS_SZ;                                          \
        GLDS16(ybase + ((size_t)(((s) * 4 + g0) * TP_) + t0 + rr0) * 16, bb + row0 * 16); \
        GLDS16(ybase + ((size_t)(((s) * 4 + g1) * TP_) + t0 + rr1) * 16, bb + row1 * 16); \
        if ((tid & 63) < 8)                                                              \
            GLDS16(ybase + ((size_t)(((s) * 4 + g2) * TP_) + t0 + rr2) * 16, bb + row2 * 16); \
    } while (0)

#define LOADA(dst, s)                                                                    \
    do {                                                                                 \
        _Pragma("unroll")                                                                \
        for (int u = 0; u < 12; ++u)                                                     \
            dst[u] = *(const s16x8*)(abase + (size_t)(s) * 24576 + (u >> 2) * 8192 + (u & 3) * 1024); \
    } while (0)

#define BODY(s, CUR, NXT)                                                                \
    do {                                                                                 \
        asm volatile("" ::: "memory");                                                   \
        __builtin_amdgcn_s_barrier();                                                    \
        asm volatile("" ::: "memory");                                                   \
        __builtin_amdgcn_sched_barrier(0);                                               \
        if ((s) <= 13) STAGEB((s) + 2);                                                  \
        if ((s) <= 14) LOADA(NXT, (s) + 1);                                              \
        {                                                                                \
            const char* bbuf = smem + ((s) % NBUF) * XS_SZ;                              \
            __builtin_amdgcn_s_setprio(1);                                               \
            _Pragma("unroll")                                                            \
            for (int tap = 0; tap < 3; ++tap) {                                          \
                s16x8 bq[4];                                                             \
                _Pragma("unroll")                                                        \
                for (int n = 0; n < 4; ++n)                                              \
                    bq[n] = *(const s16x8*)(bbuf + xs_lane + tap * 16 + n * 256);        \
                _Pragma("unroll")                                                        \
                for (int m = 0; m < 4; ++m)                                              \
                    _Pragma("unroll")                                                    \
                    for (int n = 0; n < 4; ++n)                                          \
                        acc[m][n] = __builtin_amdgcn_mfma_f32_16x16x32_bf16(             \
                            CUR[tap * 4 + m], bq[n], acc[m][n], 0, 0, 0);                \
            }                                                                            \
            __builtin_amdgcn_s_setprio(0);                                               \
        }                                                                                \
    } while (0)

    // prologue: B(0), B(1) in flight; A(0) in regs (issued after, drains B on first use)
    STAGEB(0);
    STAGEB(1);
    LOADA(afA, 0);

    for (int it = 0; it < 8; ++it) {
        const int s0 = it * 2;
        BODY(s0, afA, afB);
        BODY(s0 + 1, afB, afA);
    }
#undef BODY
#undef LOADA
#undef STAGEB

    // epilogue: out = alpha*(G + cy3) - beta*cx3
    const int lr = lane >> 4, lc = lane & 15;
    const int o0 = ob * 128 + wr * 64;
    const int tw = t0 + wc * 64;
    const float* al  = alpha + b * COUT_ + o0;
    const float* be  = beta  + b * COUT_ + o0;
    const float* cxb = cxp + b * CXP_;
    const float* cyb = cyp + b * CXP_;
    float* op = out + ((size_t)(b * COUT_ + o0)) * T_;

#pragma unroll
    for (int n = 0; n < 4; ++n) {
        int t = tw + n * 16 + lc;
        float cx3 = cxb[t] + cxb[t + 1] + cxb[t + 2];
        float cy3 = cyb[t] + cyb[t + 1] + cyb[t + 2];
#pragma unroll
        for (int m = 0; m < 4; ++m)
#pragma unroll
            for (int q = 0; q < 4; ++q) {
                int o = m * 16 + lr * 4 + q;
                op[(size_t)o * T_ + t] = al[o] * (acc[m][n][q] + cy3) - be[o] * cx3;
            }
    }
}

extern "C" void kernel_launch(void* const* d_in, const int* in_sizes, int n_in,
                              void* d_out, int out_size, void* d_ws, size_t ws_size,
                              hipStream_t stream) {
    const float* x       = (const float*)d_in[0];
    const float* c_trg   = (const float*)d_in[1];
    const float* style_w = (const float*)d_in[2];
    const float* style_b = (const float*)d_in[3];
    const float* conv_w  = (const float*)d_in[4];
    float* out = (float*)d_out;
    float* ws  = (float*)d_ws;

    float* s_buf = ws;                      // 8192
    float* alpha = ws + 8192;               // 8192
    float* beta  = ws + 16384;              // 8192
    float* cxp   = ws + 24576;              // 32800
    float* cyp   = ws + 57376;              // 32800
    float* W1    = ws + 90176;              // 262144
    float* W2    = ws + 352320;             // 262144
    u16*   wpk   = (u16*)(ws + 614464);     // 786432 u16
    u16*   ybf   = (u16*)(ws + 1007680);    // 16*64*2064*8 u16 (~33.8 MB)

    hipMemsetAsync(cxp, 0, (size_t)2 * CXP_ * B_ * sizeof(float), stream);

    k_style <<<dim3((B_ * CIN_) / 256), 256, 0, stream>>>(c_trg, style_w, style_b, s_buf);
    k_wsum  <<<dim3((COUT_ * CIN_) / 256), 256, 0, stream>>>(conv_w, W1, W2);
    k_prep_w<<<dim3((COUT_ * CIN_ * K_) / 256), 256, 0, stream>>>(conv_w, wpk);
    k_stats2<<<dim3(B_ * COUT_), 64, 0, stream>>>(s_buf, W1, W2, alpha, beta);
    k_ytrans<<<dim3(T_ / 256, 8, B_), 256, 0, stream>>>(x, s_buf, ybf, cxp, cyp);
    k_conv  <<<dim3(512), 512, 0, stream>>>(wpk, ybf, alpha, beta, cxp, cyp, out);
}

// Round 6
// 186.261 us; speedup vs baseline: 1.0324x; 1.0324x over previous
//
#include <hip/hip_runtime.h>
#include <hip/hip_bf16.h>
#include <stdint.h>

#define B_    16
#define CIN_  512
#define COUT_ 512
#define K_    3
#define T_    2048
#define S_    128
#define TP_   2064          // padded t rows: row = t+8, 8-row zero halo each side
#define CXP_  2050          // padded column-sum: idx = t+1, zero at both ends

#define ASZ   24576         // A tile per step: 3 tap x 8 grp x 1KB
#define BSZ   17408         // B tile per step: 4 g x 272 rows x 16B
#define BUFSZ (ASZ + BSZ)   // 41984
#define NBUF  3             // triple buffer -> counted vmcnt possible

#define LIN_SCALE  0.08838834764831845f   // 1/sqrt(128)
#define CONV_SCALE 0.014731391274719739f  // 1/sqrt(512*9)

typedef unsigned short u16;
typedef short s16x8 __attribute__((ext_vector_type(8)));
typedef float f32x4 __attribute__((ext_vector_type(4)));
typedef u16 u16x8 __attribute__((ext_vector_type(8)));

__device__ __forceinline__ u16 bf16r(float f) {
    uint32_t u = __float_as_uint(f);
    return (u16)((u + 0x7FFFu + ((u >> 16) & 1u)) >> 16);   // RNE
}

#define GLDS16(gsrc, ldst) \
    __builtin_amdgcn_global_load_lds((__attribute__((address_space(1))) void*)(gsrc), \
                                     (__attribute__((address_space(3))) void*)(ldst), 16, 0, 0)
#define GLDS4(gsrc, ldst) \
    __builtin_amdgcn_global_load_lds((__attribute__((address_space(1))) void*)(gsrc), \
                                     (__attribute__((address_space(3))) void*)(ldst), 4, 0, 0)

// ---------------- K1: style projection  s[b,i]
__global__ void k_style(const float* __restrict__ c_trg,
                        const float* __restrict__ style_w,
                        const float* __restrict__ style_b,
                        float* __restrict__ s_out) {
    int idx = blockIdx.x * 256 + threadIdx.x;       // 0..8191
    int b = idx >> 9, i = idx & 511;
    const float4* c4 = reinterpret_cast<const float4*>(c_trg + b * S_);
    const float4* w4 = reinterpret_cast<const float4*>(style_w + (size_t)i * S_);
    float acc = 0.f;
#pragma unroll
    for (int j = 0; j < S_ / 4; ++j) {
        float4 a = c4[j], w = w4[j];
        acc += a.x * w.x + a.y * w.y + a.z * w.z + a.w * w.w;
    }
    s_out[idx] = acc * LIN_SCALE + style_b[i];
}

// ---------------- K2: alpha/beta per (b,o) directly from conv_w; s staged in LDS.
// One block per o; each thread owns 2 i's; accumulate over all 16 b in registers.
__global__ __launch_bounds__(256) void k_stats3(
    const float* __restrict__ s, const float* __restrict__ conv_w,
    float* __restrict__ alpha, float* __restrict__ beta) {
    __shared__ float sl[B_ * CIN_];          // 32 KB
    __shared__ float red[4][32];
    __shared__ float tot[32];
    const int tid = threadIdx.x, o = blockIdx.x;
    const int lane = tid & 63, wid = tid >> 6;
#pragma unroll
    for (int r = 0; r < 8; ++r) {
        float4 v = *(const float4*)(s + r * 1024 + tid * 4);
        *(float4*)(sl + r * 1024 + tid * 4) = v;
    }
    __syncthreads();
    const float* wr = conv_w + (size_t)o * (CIN_ * K_) + tid * 6;
    float a0 = wr[0] + 1.f, a1 = wr[1] + 1.f, a2 = wr[2] + 1.f;
    float b0 = wr[3] + 1.f, b1 = wr[4] + 1.f, b2 = wr[5] + 1.f;
    float W1a = a0 + a1 + a2, W2a = a0 * a0 + a1 * a1 + a2 * a2;
    float W1b = b0 + b1 + b2, W2b = b0 * b0 + b1 * b1 + b2 * b2;
    int i = tid * 2;
    float psum[16], psq[16];
#pragma unroll
    for (int b = 0; b < 16; ++b) {
        float sa = sl[b * CIN_ + i], sb2 = sl[b * CIN_ + i + 1];
        psum[b] = sa * W1a + sb2 * W1b;
        psq[b]  = sa * sa * W2a + sb2 * sb2 * W2b;
    }
#pragma unroll
    for (int off = 32; off; off >>= 1)
#pragma unroll
        for (int b = 0; b < 16; ++b) {
            psum[b] += __shfl_down(psum[b], off);
            psq[b]  += __shfl_down(psq[b], off);
        }
    if (lane == 0)
#pragma unroll
        for (int b = 0; b < 16; ++b) { red[wid][b] = psum[b]; red[wid][16 + b] = psq[b]; }
    __syncthreads();
    if (tid < 32) tot[tid] = red[0][tid] + red[1][tid] + red[2][tid] + red[3][tid];
    __syncthreads();
    if (tid < 16) {
        float mean  = CONV_SCALE * tot[tid] * (1.0f / (CIN_ * K_));
        float demod = rsqrtf(CONV_SCALE * CONV_SCALE * tot[16 + tid] + 1e-8f);
        alpha[tid * COUT_ + o] = demod * CONV_SCALE;
        beta[tid * COUT_ + o]  = demod * mean;
    }
}

// ---------------- K3: weight prepack into MFMA fragment-image order (bf16).
// wpk flat idx = ((((ob*16 + step)*3 + tap)*8 + grp)*64 + lane)*8 + j
// holds cw[o = ob*128+grp*16+(lane&15)][i = step*32+(lane>>4)*8+j][tap]
__global__ void k_prep_w(const float* __restrict__ conv_w, u16* __restrict__ wpk) {
    int idx = blockIdx.x * 256 + threadIdx.x;   // < 786432
    int j    = idx & 7;
    int lane = (idx >> 3) & 63;
    int grp  = (idx >> 9) & 7;
    int rest = idx >> 12;          // tap + 3*(step + 16*ob)
    int tap  = rest % 3;
    int so   = rest / 3;
    int step = so & 15, ob = so >> 4;
    int o = ob * 128 + grp * 16 + (lane & 15);
    int i = step * 32 + (lane >> 4) * 8 + j;
    wpk[idx] = bf16r(conv_w[((size_t)o * CIN_ + i) * 3 + tap]);
}

// ---------------- K4: y = s*x -> bf16, octet-interleaved + t-halo; 64 channels/block,
// 8 atomicAdds per (b,t) for column sums.
__global__ void k_ytrans(const float* __restrict__ x, const float* __restrict__ s,
                         u16* __restrict__ ybf,
                         float* __restrict__ cxp, float* __restrict__ cyp) {
    int tid = threadIdx.x;
    int t = blockIdx.x * 256 + tid;
    int og = blockIdx.y, b = blockIdx.z;
    float ax = 0.f, ay = 0.f;
#pragma unroll
    for (int o8 = 0; o8 < 8; ++o8) {
        int oct = og * 8 + o8;
        const float* xb = x + ((size_t)(b * CIN_ + oct * 8)) * T_ + t;
        const float* sb = s + b * CIN_ + oct * 8;
        u16x8 pv;
#pragma unroll
        for (int j = 0; j < 8; ++j) {
            float xv = xb[(size_t)j * T_];
            float yv = sb[j] * xv;
            ax += xv; ay += yv;
            pv[j] = bf16r(yv);
        }
        *(u16x8*)(ybf + (((size_t)(b * 64 + oct)) * TP_ + t + 8) * 8) = pv;
    }
    atomicAdd(&cxp[b * CXP_ + t + 1], ax);
    atomicAdd(&cyp[b * CXP_ + t + 1], ay);
    if (blockIdx.x == 0 && tid < 64) {      // zero both halos for this block's 8 octs
        u16x8 z = {0, 0, 0, 0, 0, 0, 0, 0};
        int oct = og * 8 + (tid >> 3);
        *(u16x8*)(ybf + (((size_t)(b * 64 + oct)) * TP_ + (tid & 7)) * 8) = z;
        *(u16x8*)(ybf + (((size_t)(b * 64 + oct)) * TP_ + 2056 + (tid & 7)) * 8) = z;
    }
}

// ---------------- K5: MFMA conv v4. 128o x 256t tile, 8 waves, 126KB LDS.
// Triple-buffered A+B staging via global_load_lds, counted s_waitcnt vmcnt(6)
// (never 0 in the loop), raw s_barrier, no sched pinning. Uniform 6 GLDS/thread/step.
__global__ __launch_bounds__(512) void k_conv(
    const u16* __restrict__ wpk, const u16* __restrict__ ybf,
    const float* __restrict__ alpha, const float* __restrict__ beta,
    const float* __restrict__ cxp, const float* __restrict__ cyp,
    float* __restrict__ out) {

    __shared__ __align__(16) char smem[NBUF * BUFSZ];   // 125952 B

    const int tid  = threadIdx.x;
    const int lane = tid & 63;
    const int w    = tid >> 6;
    const int wr   = w >> 2, wc = w & 3;   // wave grid: 2 (o) x 4 (t)

    // XCD swizzle: 512 blocks, 64 contiguous wgs per XCD -> 2 batches per XCD L2
    const int bid = blockIdx.x;
    const int wg  = (bid & 7) * 64 + (bid >> 3);
    const int b   = wg >> 5;           // 32 wgs per batch
    const int ob  = (wg >> 3) & 3;     // 4 o-blocks of 128
    const int t0  = (wg & 7) * 256;    // 8 t-blocks of 256

    // ---- per-thread staging addresses (uniform: 3x16B A + 2x16B B + 1x4B B = 6 ops)
    const char* abase = (const char*)wpk + (size_t)ob * 393216;
    const int aoff0 = (3 * w + 0) * 1024 + lane * 16;     // same offset in src and LDS
    const int aoff1 = (3 * w + 1) * 1024 + lane * 16;
    const int aoff2 = (3 * w + 2) * 1024 + lane * 16;

    const char* ybase = (const char*)ybf + ((size_t)b * 64) * (TP_ * 16);
    const int c0 = tid, c1 = 512 + tid;
    const int g0 = c0 / 272, rr0 = c0 - g0 * 272;
    const int g1 = c1 / 272, rr1 = c1 - g1 * 272;
    const size_t boff0 = ((size_t)g0 * TP_ + t0 + rr0) * 16;
    const size_t boff1 = ((size_t)g1 * TP_ + t0 + rr1) * 16;
    const int rowf = 1024 + ((tid & 255) >> 2);           // g=3, rr = rowf-816
    const size_t boff2 = ((size_t)3 * TP_ + t0 + (rowf - 816)) * 16 + (tid & 3) * 4;
    const int bdst0 = ASZ + c0 * 16, bdst1 = ASZ + c1 * 16;
    const int bdst2 = ASZ + 16384 + (tid & 255) * 4;

    // ---- fragment read offsets
    const int as_lane = wr * 4096 + lane * 16;                               // + tap*8192 + m*1024
    const int xs_lane = ASZ + (lane >> 4) * 4352 + ((lane & 15) + 7) * 16 + wc * 1024;  // + tap*16 + n*256

    f32x4 acc[4][4] = {};

#define STAGE(s)                                                             \
    do {                                                                     \
        char* dst = smem + ((s) % NBUF) * BUFSZ;                             \
        const char* asrc = abase + (size_t)(s) * ASZ;                        \
        const char* bsrc = ybase + (size_t)(s) * (4 * TP_ * 16);             \
        GLDS16(asrc + aoff0, dst + aoff0);                                   \
        GLDS16(asrc + aoff1, dst + aoff1);                                   \
        GLDS16(asrc + aoff2, dst + aoff2);                                   \
        GLDS16(bsrc + boff0, dst + bdst0);                                   \
        GLDS16(bsrc + boff1, dst + bdst1);                                   \
        GLDS4 (bsrc + boff2, dst + bdst2);                                   \
    } while (0)

    STAGE(0);
    STAGE(1);

#pragma unroll
    for (int s = 0; s < 16; ++s) {
        if (s < 15) asm volatile("s_waitcnt vmcnt(6)" ::: "memory");   // stage(s) landed, stage(s+1) in flight
        else        asm volatile("s_waitcnt vmcnt(0)" ::: "memory");
        __builtin_amdgcn_s_barrier();
        asm volatile("" ::: "memory");
        if (s + 2 < 16) STAGE(s + 2);          // into buf freed at this barrier

        const char* base = smem + (s % NBUF) * BUFSZ;
        __builtin_amdgcn_s_setprio(1);
#pragma unroll
        for (int tap = 0; tap < 3; ++tap) {
            s16x8 af[4], bq[4];
#pragma unroll
            for (int m = 0; m < 4; ++m)
                af[m] = *(const s16x8*)(base + tap * 8192 + as_lane + m * 1024);
#pragma unroll
            for (int n = 0; n < 4; ++n)
                bq[n] = *(const s16x8*)(base + xs_lane + tap * 16 + n * 256);
#pragma unroll
            for (int m = 0; m < 4; ++m)
#pragma unroll
                for (int n = 0; n < 4; ++n)
                    acc[m][n] = __builtin_amdgcn_mfma_f32_16x16x32_bf16(af[m], bq[n], acc[m][n], 0, 0, 0);
        }
        __builtin_amdgcn_s_setprio(0);
    }
#undef STAGE

    // epilogue: out = alpha*(G + cy3) - beta*cx3
    const int lr = lane >> 4, lc = lane & 15;
    const int o0 = ob * 128 + wr * 64;
    const int tw = t0 + wc * 64;
    const float* al  = alpha + b * COUT_ + o0;
    const float* be  = beta  + b * COUT_ + o0;
    const float* cxb = cxp + b * CXP_;
    const float* cyb = cyp + b * CXP_;
    float* op = out + ((size_t)(b * COUT_ + o0)) * T_;

#pragma unroll
    for (int n = 0; n < 4; ++n) {
        int t = tw + n * 16 + lc;
        float cx3 = cxb[t] + cxb[t + 1] + cxb[t + 2];
        float cy3 = cyb[t] + cyb[t + 1] + cyb[t + 2];
#pragma unroll
        for (int m = 0; m < 4; ++m)
#pragma unroll
            for (int q = 0; q < 4; ++q) {
                int o = m * 16 + lr * 4 + q;
                op[(size_t)o * T_ + t] = al[o] * (acc[m][n][q] + cy3) - be[o] * cx3;
            }
    }
}

extern "C" void kernel_launch(void* const* d_in, const int* in_sizes, int n_in,
                              void* d_out, int out_size, void* d_ws, size_t ws_size,
                              hipStream_t stream) {
    const float* x       = (const float*)d_in[0];
    const float* c_trg   = (const float*)d_in[1];
    const float* style_w = (const float*)d_in[2];
    const float* style_b = (const float*)d_in[3];
    const float* conv_w  = (const float*)d_in[4];
    float* out = (float*)d_out;
    float* ws  = (float*)d_ws;

    float* s_buf = ws;                      // 8192
    float* alpha = ws + 8192;               // 8192
    float* beta  = ws + 16384;              // 8192
    float* cxp   = ws + 24576;              // 32800
    float* cyp   = ws + 57376;              // 32800
    u16*   wpk   = (u16*)(ws + 90176);      // 786432 u16
    u16*   ybf   = (u16*)(ws + 483392);     // 16*64*2064*8 u16 (~33.8 MB)

    hipMemsetAsync(cxp, 0, (size_t)2 * CXP_ * B_ * sizeof(float), stream);

    k_style <<<dim3((B_ * CIN_) / 256), 256, 0, stream>>>(c_trg, style_w, style_b, s_buf);
    k_prep_w<<<dim3((COUT_ * CIN_ * K_) / 256), 256, 0, stream>>>(conv_w, wpk);
    k_stats3<<<dim3(COUT_), 256, 0, stream>>>(s_buf, conv_w, alpha, beta);
    k_ytrans<<<dim3(T_ / 256, 8, B_), 256, 0, stream>>>(x, s_buf, ybf, cxp, cyp);
    k_conv  <<<dim3(512), 512, 0, stream>>>(wpk, ybf, alpha, beta, cxp, cyp, out);
}